// Round 3
// baseline (375.140 us; speedup 1.0000x reference)
//
#include <hip/hip_runtime.h>

// OverlapAdd: y[b,c,t] = sum_{k=0..3} x[b, k*128+c, t-k]  (t-k>=0 else dropped)
// B=8, C_in=512, c_out=128, T=16000, fp32.
// Memory floor: 262 MB read + 65.5 MB write -> ~52 us @ 6.3 TB/s.
// R2: same as R1 but nontemporal stores via native clang vector type
// (builtin rejects HIP_vector_type<float,4>*).

#define OA_T4    4000                  // float4 per row
#define OA_T8    2000                  // float4-pairs per row
#define OA_NPAIR (1024 * OA_T8)        // 2,048,000 = 8000 blocks * 256

typedef float vfloat4 __attribute__((ext_vector_type(4)));

__global__ __launch_bounds__(256) void OverlapAdd_19490561590070_kernel(
    const float4* __restrict__ x, float4* __restrict__ y) {
    int i = blockIdx.x * 256 + threadIdx.x;   // pair index, grid is exact

    int row = i / OA_T8;                       // row = b*128 + c, in [0,1024)
    int t8  = i - row * OA_T8;                 // pair index within row
    int b   = row >> 7;
    int c   = row & 127;

    // k=0 stream base (float4 units); k strides by 128 rows of T4 float4
    const float4* p0 = x + ((long)(b * 512 + c)) * OA_T4 + 2 * t8;
    const float4* p1 = p0 + 128L * OA_T4;
    const float4* p2 = p0 + 256L * OA_T4;
    const float4* p3 = p0 + 384L * OA_T4;

    float4 B00 = p0[0], B01 = p0[1];
    float4 B10 = p1[0], B11 = p1[1];
    float4 B20 = p2[0], B21 = p2[1];
    float4 B30 = p3[0], B31 = p3[1];

    float4 A1, A2, A3;                         // x_k[t-4 .. t-1]
    if (t8 > 0) {
        A1 = p1[-1];
        A2 = p2[-1];
        A3 = p3[-1];
    } else {                                   // row start: left-pad zeros
        A1 = make_float4(0.f, 0.f, 0.f, 0.f);
        A2 = A1;
        A3 = A1;
    }

    // Same left-to-right add order as reference: ((k0+k1)+k2)+k3
    vfloat4 o0, o1;
    o0.x = B00.x + A1.w  + A2.z  + A3.y;
    o0.y = B00.y + B10.x + A2.w  + A3.z;
    o0.z = B00.z + B10.y + B20.x + A3.w;
    o0.w = B00.w + B10.z + B20.y + B30.x;
    o1.x = B01.x + B10.w + B20.z + B30.y;
    o1.y = B01.y + B11.x + B20.w + B30.z;
    o1.z = B01.z + B11.y + B21.x + B30.w;
    o1.w = B01.w + B11.z + B21.y + B31.x;

    vfloat4* yp = reinterpret_cast<vfloat4*>(y + (long)row * OA_T4 + 2 * t8);
    __builtin_nontemporal_store(o0, yp);
    __builtin_nontemporal_store(o1, yp + 1);
}

extern "C" void kernel_launch(void* const* d_in, const int* in_sizes, int n_in,
                              void* d_out, int out_size, void* d_ws, size_t ws_size,
                              hipStream_t stream) {
    const float4* x = (const float4*)d_in[0];
    float4*       y = (float4*)d_out;
    // OA_NPAIR = 2,048,000 threads = exactly 8000 blocks of 256
    OverlapAdd_19490561590070_kernel<<<dim3(OA_NPAIR / 256), dim3(256), 0, stream>>>(x, y);
}

// Round 4
// 361.606 us; speedup vs baseline: 1.0374x; 1.0374x over previous
//
#include <hip/hip_runtime.h>

// OverlapAdd: y[b,c,t] = sum_{k=0..3} x[b, k*128+c, t-k]  (t-k>=0 else dropped)
// B=8, C_in=512, c_out=128, T=16000, fp32.
// Memory floor: 262 MB read + 65.5 MB write -> ~52 us @ 6.6 TB/s (fill-measured).
// R4 = exact revert to R1 (best measured: 357 us end-to-end). R3's NT-store
// + 2-wide variant regressed to 375; this run calibrates noise vs real delta.
// Note: dur_us includes harness reset (~250-300 us of fills + x-restore), so
// kernel-controlled share is only ~50-110 us.

#define OA_T4   4000                 // T/4 float4 per row
#define OA_N4   (1024 * OA_T4)       // (B*c_out) rows * T4

__global__ __launch_bounds__(256) void OverlapAdd_19490561590070_kernel(
    const float4* __restrict__ x, float4* __restrict__ y) {
    int i = blockIdx.x * 256 + threadIdx.x;
    if (i >= OA_N4) return;

    int row = i / OA_T4;             // row = b*128 + c, in [0,1024)
    int t4  = i - row * OA_T4;       // float4 index within the row
    int b   = row >> 7;
    int c   = row & 127;

    // input row base (in float4 units) for k=0; k strides by 128 rows
    const float4* p0 = x + ((long)(b * 512 + c)) * OA_T4 + t4;
    const float4* p1 = p0 + 128L * OA_T4;
    const float4* p2 = p0 + 256L * OA_T4;
    const float4* p3 = p0 + 384L * OA_T4;

    float4 B0 = *p0;
    float4 B1 = *p1;
    float4 B2 = *p2;
    float4 B3 = *p3;

    float4 A1, A2, A3;               // x_k[t-4 .. t-1]
    if (t4 > 0) {
        A1 = p1[-1];
        A2 = p2[-1];
        A3 = p3[-1];
    } else {                         // t==0: left-pad with zeros
        A1 = make_float4(0.f, 0.f, 0.f, 0.f);
        A2 = A1;
        A3 = A1;
    }

    // Same left-to-right add order as the reference: ((c0+s1)+s2)+s3
    float4 o;
    o.x = B0.x + A1.w + A2.z + A3.y;
    o.y = B0.y + B1.x + A2.w + A3.z;
    o.z = B0.z + B1.y + B2.x + A3.w;
    o.w = B0.w + B1.z + B2.y + B3.x;

    y[i] = o;
}

extern "C" void kernel_launch(void* const* d_in, const int* in_sizes, int n_in,
                              void* d_out, int out_size, void* d_ws, size_t ws_size,
                              hipStream_t stream) {
    const float4* x = (const float4*)d_in[0];
    float4*       y = (float4*)d_out;
    // OA_N4 = 4,096,000 threads = exactly 16000 blocks of 256
    OverlapAdd_19490561590070_kernel<<<dim3(OA_N4 / 256), dim3(256), 0, stream>>>(x, y);
}